// Round 5
// baseline (4758.540 us; speedup 1.0000x reference)
//
#include <hip/hip_runtime.h>
#include <hip/hip_cooperative_groups.h>

namespace cg = cooperative_groups;

typedef __attribute__((ext_vector_type(8))) short bf16x8;
typedef __attribute__((ext_vector_type(4))) short bf16x4;
typedef __attribute__((ext_vector_type(4))) float f32x4;

#define TFULL 8192
#define RC 128
#define NB 40
#define BATCH 4
#define SKIP_SZ 4096

// LDS: 4 planes of [64 col][256 B], XOR-swizzled (byte ^= (col&7)<<4) so
// ds_read_b128 column-slices spread over 8 slots (<=2-way, free).
//   plane 0/1: staged X hi/lo (current tap; tap1 resident at epilogue)
//   plane 2/3: gated hi/lo
#define XPLANE 16384
#define GBASE  (2 * XPLANE)
#define LDS_BYTES (4 * XPLANE)   // 65536 B -> 2 WG/CU (m132 precedent)

__device__ __forceinline__ unsigned short f2bf(float f) {
    unsigned u = __builtin_bit_cast(unsigned, f);
    u += 0x7FFFu + ((u >> 16) & 1u);          // round-to-nearest-even
    return (unsigned short)(u >> 16);
}
__device__ __forceinline__ float bf2f(unsigned short h) {
    unsigned u = ((unsigned)h) << 16;
    return __builtin_bit_cast(float, u);
}
// tanh(y)*sigmoid(y) via one fast exp: e=e^-y; (1-e^2)/(1+e^2) * 1/(1+e).
// Clamp keeps e^2 finite; saturation exact at the clamp.
__device__ __forceinline__ float gatef(float y) {
    float yc = fminf(fmaxf(y, -30.f), 30.f);
    float e  = __expf(-yc);
    float e2 = e * e;
    return (1.f - e2) * __builtin_amdgcn_rcpf(1.f + e2)
                      * __builtin_amdgcn_rcpf(1.f + e);
}

// ---------------------------------------------------------------------------
// Pre-pass 1: transpose x [B][128ch][8192col] fp32 -> hi/lo bf16 [B][col][ch]
// ---------------------------------------------------------------------------
__global__ __launch_bounds__(256) void xpose_split(
    const float* __restrict__ x,
    unsigned short* __restrict__ Xh, unsigned short* __restrict__ Xl)
{
    __shared__ float t[32][65];
    const int col0 = blockIdx.x * 64;
    const int ch0  = blockIdx.y * 32;
    const int b    = blockIdx.z;
    const int tid  = threadIdx.x;
    const int tx = tid & 63, ty = tid >> 6;
#pragma unroll
    for (int i = 0; i < 8; ++i) {
        int ch = ty + i * 4;
        t[ch][tx] = x[((size_t)(b * RC + ch0 + ch)) * TFULL + col0 + tx];
    }
    __syncthreads();
    for (int idx = tid; idx < 64 * 32; idx += 256) {
        int col = idx >> 5, ch = idx & 31;
        float v = t[ch][col];
        unsigned short h = f2bf(v);
        unsigned short l = f2bf(v - bf2f(h));
        size_t off = ((size_t)(b * TFULL + col0 + col)) * RC + ch0 + ch;
        Xh[off] = h;
        Xl[off] = l;
    }
}

// ---------------------------------------------------------------------------
// Pre-pass 2: pack weights into per-MFMA-A-fragment layout, hi/lo bf16.
// A[m][k]: lane l holds rows m=16*mf+(l&15), k = 32*ks + (l>>4)*8 + j.
// Dilated k = tap*128 + i. Dst flat: ((blk*KS*8 + ks*8 + mf)*64 + lane)*8 + j.
// ---------------------------------------------------------------------------
__global__ __launch_bounds__(256) void wpack(
    const float* __restrict__ Wd, const float* __restrict__ Wr, const float* __restrict__ Ws,
    unsigned short* __restrict__ Wdh, unsigned short* __restrict__ Wdl,
    unsigned short* __restrict__ Wrh, unsigned short* __restrict__ Wrl,
    unsigned short* __restrict__ Wsh, unsigned short* __restrict__ Wsl)
{
    const int Nd = NB * 4096;
    const int Nr = NB * 2048;
    int id = blockIdx.x * 256 + threadIdx.x;
    const float* src;
    unsigned short *dh, *dl;
    int blk, rloc;
    bool dil = false;
    size_t dbase;
    if (id < Nd)               { dil = true; blk = id >> 12; rloc = id & 4095; dh = Wdh; dl = Wdl; src = Wd; dbase = (size_t)id * 8; }
    else if (id < Nd + Nr)     { int t = id - Nd;      blk = t >> 11; rloc = t & 2047; dh = Wrh; dl = Wrl; src = Wr; dbase = (size_t)t * 8; }
    else if (id < Nd + 2 * Nr) { int t = id - Nd - Nr; blk = t >> 11; rloc = t & 2047; dh = Wsh; dl = Wsl; src = Ws; dbase = (size_t)t * 8; }
    else return;
    const int ks = rloc >> 9, mf = (rloc >> 6) & 7, lane = rloc & 63;
    const int m = mf * 16 + (lane & 15);
    const int kb = ks * 32 + ((lane >> 4) << 3);
    bf16x8 hv, lv;
#pragma unroll
    for (int j = 0; j < 8; ++j) {
        int k = kb + j;
        float w;
        if (dil) {
            int tap = k >> 7, i = k & 127;
            w = src[((((size_t)blk * 128 + m) * 128) + i) * 2 + tap];
        } else {
            w = src[(((size_t)blk * 128 + m) * 128) + k];
        }
        unsigned short h = f2bf(w);
        hv[j] = (short)h;
        lv[j] = (short)f2bf(w - bf2f(h));
    }
    *(bf16x8*)(dh + dbase) = hv;
    *(bf16x8*)(dl + dbase) = lv;
}

// ---------------------------------------------------------------------------
// One work unit = (batch, 64-col tile) of one WaveNet block. Shared by the
// cooperative and fallback kernels. Numerics: 3-product hi/lo bf16 split.
// ---------------------------------------------------------------------------
__device__ __forceinline__ void process_unit(
    char* lds, int u, int d, int col0,
    const unsigned short* __restrict__ curh, const unsigned short* __restrict__ curl,
    unsigned short* __restrict__ nxth, unsigned short* __restrict__ nxtl,
    const unsigned short* __restrict__ Wdh_i, const unsigned short* __restrict__ Wdl_i,
    const unsigned short* __restrict__ Wrh_i, const unsigned short* __restrict__ Wrl_i,
    const unsigned short* __restrict__ Wsh_i, const unsigned short* __restrict__ Wsl_i,
    const float* __restrict__ br, const float* __restrict__ bs,
    float* __restrict__ skip)
{
    const int tid  = threadIdx.x;
    const int lane = tid & 63;
    const int wave = tid >> 6;
    const int m0   = wave * 32;
    const int l15  = lane & 15, lq = lane >> 4;
    const int b    = u & 3;
    const int tile = u >> 2;
    const int tile0 = col0 + tile * 64;
    const size_t xbase = (size_t)b * TFULL * RC;

    f32x4 acc[2][4];
#pragma unroll
    for (int mf = 0; mf < 2; ++mf)
#pragma unroll
        for (int nf = 0; nf < 4; ++nf) acc[mf][nf] = (f32x4){0.f, 0.f, 0.f, 0.f};

#pragma unroll
    for (int tap = 0; tap < 2; ++tap) {
        __syncthreads();   // WAR: previous reads of X planes done
        {   // stage this tap's hi+lo: 64 cols x 256 B per plane, swizzled
            const int colq  = tid >> 5;        // 0..7
            const int hl    = (tid >> 4) & 1;
            const int chunk = tid & 15;        // 16 B unit within col row
            const unsigned short* src = hl ? curl : curh;
            const int cshift = tap ? 0 : d;
            const int sbyte  = (chunk * 16) ^ (colq << 4);   // (cq&7)==colq
            float4 v[8];
#pragma unroll
            for (int q = 0; q < 8; ++q) {
                int cg_ = tile0 + q * 8 + colq;
                cg_ = cg_ > TFULL - 1 ? TFULL - 1 : cg_;  // tail clamp
                cg_ -= cshift;
                v[q] = *(const float4*)(src + xbase + (size_t)cg_ * RC + chunk * 8);
            }
            char* plane = lds + hl * XPLANE;
#pragma unroll
            for (int q = 0; q < 8; ++q)
                *(float4*)(plane + (q * 8 + colq) * 256 + sbyte) = v[q];
        }
        __syncthreads();

#pragma unroll
        for (int kk = 0; kk < 4; ++kk) {
            const int ks = tap * 4 + kk;
            bf16x8 ah[2], al[2];
#pragma unroll
            for (int mf = 0; mf < 2; ++mf) {
                size_t wi = ((size_t)(ks * 8 + wave * 2 + mf) * 64 + lane) * 8;
                ah[mf] = *(const bf16x8*)(Wdh_i + wi);
                al[mf] = *(const bf16x8*)(Wdl_i + wi);
            }
            bf16x8 bh[4], bl[4];
#pragma unroll
            for (int nf = 0; nf < 4; ++nf) {
                const int col = nf * 16 + l15;
                const int byo = (kk * 64 + lq * 16) ^ ((col & 7) << 4);
                const char* pb = lds + col * 256 + byo;
                bh[nf] = *(const bf16x8*)pb;
                bl[nf] = *(const bf16x8*)(pb + XPLANE);
            }
#pragma unroll
            for (int mf = 0; mf < 2; ++mf)
#pragma unroll
                for (int nf = 0; nf < 4; ++nf) {
                    acc[mf][nf] = __builtin_amdgcn_mfma_f32_16x16x32_bf16(ah[mf], bh[nf], acc[mf][nf], 0, 0, 0);
                    acc[mf][nf] = __builtin_amdgcn_mfma_f32_16x16x32_bf16(ah[mf], bl[nf], acc[mf][nf], 0, 0, 0);
                    acc[mf][nf] = __builtin_amdgcn_mfma_f32_16x16x32_bf16(al[mf], bh[nf], acc[mf][nf], 0, 0, 0);
                }
        }
    }

    // ---- gate + write gated hi/lo to LDS planes 2/3 (8B writes, swizzled)
#pragma unroll
    for (int mf = 0; mf < 2; ++mf)
#pragma unroll
        for (int nf = 0; nf < 4; ++nf) {
            const int n   = nf * 16 + l15;
            const int ch0 = m0 + mf * 16 + lq * 4;
            const int byo = (ch0 * 2) ^ ((n & 7) << 4);
            char* pg = lds + GBASE + n * 256 + byo;
            bf16x4 hv, lv;
#pragma unroll
            for (int r = 0; r < 4; ++r) {
                float g = gatef(acc[mf][nf][r]);
                unsigned short h = f2bf(g);
                hv[r] = (short)h;
                lv[r] = (short)f2bf(g - bf2f(h));
            }
            *(bf16x4*)pg = hv;
            *(bf16x4*)(pg + XPLANE) = lv;
        }
    __syncthreads();

    // ---- res & skip 1x1 GEMMs: K = 128 over gated
    f32x4 accr[2][4], accs[2][4];
#pragma unroll
    for (int mf = 0; mf < 2; ++mf)
#pragma unroll
        for (int nf = 0; nf < 4; ++nf) {
            accr[mf][nf] = (f32x4){0.f, 0.f, 0.f, 0.f};
            accs[mf][nf] = (f32x4){0.f, 0.f, 0.f, 0.f};
        }
#pragma unroll
    for (int ks = 0; ks < 4; ++ks) {
        bf16x8 rh[2], rl[2], sh[2], sl[2];
#pragma unroll
        for (int mf = 0; mf < 2; ++mf) {
            size_t wi = ((size_t)(ks * 8 + wave * 2 + mf) * 64 + lane) * 8;
            rh[mf] = *(const bf16x8*)(Wrh_i + wi);
            rl[mf] = *(const bf16x8*)(Wrl_i + wi);
            sh[mf] = *(const bf16x8*)(Wsh_i + wi);
            sl[mf] = *(const bf16x8*)(Wsl_i + wi);
        }
        bf16x8 gh[4], gl2[4];
#pragma unroll
        for (int nf = 0; nf < 4; ++nf) {
            const int col = nf * 16 + l15;
            const int byo = (ks * 64 + lq * 16) ^ ((col & 7) << 4);
            const char* pg = lds + GBASE + col * 256 + byo;
            gh[nf]  = *(const bf16x8*)pg;
            gl2[nf] = *(const bf16x8*)(pg + XPLANE);
        }
#pragma unroll
        for (int mf = 0; mf < 2; ++mf)
#pragma unroll
            for (int nf = 0; nf < 4; ++nf) {
                accr[mf][nf] = __builtin_amdgcn_mfma_f32_16x16x32_bf16(rh[mf], gh[nf],  accr[mf][nf], 0, 0, 0);
                accr[mf][nf] = __builtin_amdgcn_mfma_f32_16x16x32_bf16(rh[mf], gl2[nf], accr[mf][nf], 0, 0, 0);
                accr[mf][nf] = __builtin_amdgcn_mfma_f32_16x16x32_bf16(rl[mf], gh[nf],  accr[mf][nf], 0, 0, 0);
                accs[mf][nf] = __builtin_amdgcn_mfma_f32_16x16x32_bf16(sh[mf], gh[nf],  accs[mf][nf], 0, 0, 0);
                accs[mf][nf] = __builtin_amdgcn_mfma_f32_16x16x32_bf16(sh[mf], gl2[nf], accs[mf][nf], 0, 0, 0);
                accs[mf][nf] = __builtin_amdgcn_mfma_f32_16x16x32_bf16(sl[mf], gh[nf],  accs[mf][nf], 0, 0, 0);
            }
    }

    // ---- epilogue: residual add (input = staged tap1 in planes 0/1), store
    const int nt = TFULL - tile0 < 64 ? TFULL - tile0 : 64;
#pragma unroll
    for (int mf = 0; mf < 2; ++mf)
#pragma unroll
        for (int nf = 0; nf < 4; ++nf) {
            const int n   = nf * 16 + l15;
            const int c   = tile0 + n;
            const int ch0 = m0 + mf * 16 + lq * 4;
            const int byo = (ch0 * 2) ^ ((n & 7) << 4);
            const char* pr = lds + n * 256 + byo;
            bf16x4 ih = *(const bf16x4*)pr;
            bf16x4 il = *(const bf16x4*)(pr + XPLANE);
            const float4 brv = *(const float4*)(br + ch0);
            const float4 bsv = *(const float4*)(bs + ch0);
            bf16x4 oh, ol;
            float sk[4];
#pragma unroll
            for (int r = 0; r < 4; ++r) {
                float inv = bf2f((unsigned short)ih[r]) + bf2f((unsigned short)il[r]);
                float rv = accr[mf][nf][r] + ((const float*)&brv)[r] + inv;
                unsigned short h = f2bf(rv);
                oh[r] = (short)h;
                ol[r] = (short)f2bf(rv - bf2f(h));
                sk[r] = accs[mf][nf][r] + ((const float*)&bsv)[r];
            }
            if (n < nt) {
                const size_t off = xbase + (size_t)c * RC + ch0;
                *(bf16x4*)(nxth + off) = oh;
                *(bf16x4*)(nxtl + off) = ol;
                if (c >= TFULL - SKIP_SZ) {
                    float* sp = skip + ((size_t)b * RC + ch0) * SKIP_SZ + (c - (TFULL - SKIP_SZ));
#pragma unroll
                    for (int r = 0; r < 4; ++r) sp[(size_t)r * SKIP_SZ] = sk[r];
                }
            }
        }
}

// ---------------------------------------------------------------------------
// Cooperative fused kernel: all 40 blocks, grid.sync() between them.
// Any grid size is correct (unit-stride loop).
// ---------------------------------------------------------------------------
__global__ __launch_bounds__(256, 2) void wn_coop(
    unsigned short* Xs0h, unsigned short* Xs0l,
    unsigned short* Xs1h, unsigned short* Xs1l,
    const unsigned short* __restrict__ Wdh, const unsigned short* __restrict__ Wdl,
    const unsigned short* __restrict__ Wrh, const unsigned short* __restrict__ Wrl,
    const unsigned short* __restrict__ Wsh, const unsigned short* __restrict__ Wsl,
    const float* __restrict__ br_all, const float* __restrict__ bs_all,
    float* __restrict__ out)
{
    __shared__ char lds[LDS_BYTES];
    cg::grid_group grid = cg::this_grid();

    const unsigned short* curh = Xs0h;
    const unsigned short* curl = Xs0l;
    unsigned short* nxth = Xs1h;
    unsigned short* nxtl = Xs1l;

    int L = TFULL;
    for (int i = 0; i < NB; ++i) {
        const int d    = 1 << (i % 10);
        const int Lout = L - d;
        const int col0 = TFULL - Lout;
        const int units = ((Lout + 63) >> 6) * BATCH;

        for (int u = blockIdx.x; u < units; u += gridDim.x)
            process_unit(lds, u, d, col0, curh, curl, nxth, nxtl,
                         Wdh + (size_t)i * 32768, Wdl + (size_t)i * 32768,
                         Wrh + (size_t)i * 16384, Wrl + (size_t)i * 16384,
                         Wsh + (size_t)i * 16384, Wsl + (size_t)i * 16384,
                         br_all + (size_t)i * RC, bs_all + (size_t)i * RC,
                         out + (size_t)i * BATCH * RC * SKIP_SZ);

        __threadfence();
        grid.sync();

        // swap ping-pong (uniform, stays in SGPRs)
        const unsigned short* th = curh; const unsigned short* tl = curl;
        curh = nxth; curl = nxtl;
        nxth = (unsigned short*)th; nxtl = (unsigned short*)tl;
        L = Lout;
    }
}

// Fallback: one unit per WG, one launch per block (known-good R3 structure).
__global__ __launch_bounds__(256, 2) void wn_step(
    const unsigned short* __restrict__ curh, const unsigned short* __restrict__ curl,
    unsigned short* __restrict__ nxth, unsigned short* __restrict__ nxtl,
    const unsigned short* __restrict__ Wdh_i, const unsigned short* __restrict__ Wdl_i,
    const unsigned short* __restrict__ Wrh_i, const unsigned short* __restrict__ Wrl_i,
    const unsigned short* __restrict__ Wsh_i, const unsigned short* __restrict__ Wsl_i,
    const float* __restrict__ br, const float* __restrict__ bs,
    float* __restrict__ skip, int d, int col0)
{
    __shared__ char lds[LDS_BYTES];
    process_unit(lds, blockIdx.x, d, col0, curh, curl, nxth, nxtl,
                 Wdh_i, Wdl_i, Wrh_i, Wrl_i, Wsh_i, Wsl_i, br, bs, skip);
}

extern "C" void kernel_launch(void* const* d_in, const int* in_sizes, int n_in,
                              void* d_out, int out_size, void* d_ws, size_t ws_size,
                              hipStream_t stream) {
    const float* x  = (const float*)d_in[0];
    const float* Wd = (const float*)d_in[1];
    const float* Wr = (const float*)d_in[2];
    const float* br = (const float*)d_in[3];
    const float* Ws = (const float*)d_in[4];
    const float* bs = (const float*)d_in[5];
    float* out = (float*)d_out;

    const size_t SLOT = (size_t)BATCH * TFULL * RC;
    unsigned short* Xs0h = (unsigned short*)d_ws;
    unsigned short* Xs0l = Xs0h + SLOT;
    unsigned short* Xs1h = Xs0l + SLOT;
    unsigned short* Xs1l = Xs1h + SLOT;
    unsigned short* Wdh = Xs1l + SLOT;
    unsigned short* Wdl = Wdh + (size_t)NB * 32768;
    unsigned short* Wrh = Wdl + (size_t)NB * 32768;
    unsigned short* Wrl = Wrh + (size_t)NB * 16384;
    unsigned short* Wsh = Wrl + (size_t)NB * 16384;
    unsigned short* Wsl = Wsh + (size_t)NB * 16384;

    xpose_split<<<dim3(TFULL / 64, RC / 32, BATCH), 256, 0, stream>>>(x, Xs0h, Xs0l);
    {
        int total = NB * 4096 + 2 * NB * 2048;
        wpack<<<dim3((total + 255) / 256), 256, 0, stream>>>(Wd, Wr, Ws, Wdh, Wdl, Wrh, Wrl, Wsh, Wsl);
    }

    // Cooperative path: size grid from the occupancy query (capture-safe
    // host call), fall back to per-block launches if the launch is refused.
    int nb = 0;
    hipError_t qerr = hipOccupancyMaxActiveBlocksPerMultiprocessor(
        &nb, reinterpret_cast<const void*>(wn_coop), 256, 0);
    bool coop_ok = (qerr == hipSuccess && nb >= 1);
    if (coop_ok) {
        int gridn = nb * 256;            // 256 CUs on MI355X
        if (gridn > 512) gridn = 512;    // never need more than max units
        const unsigned short *cWdh = Wdh, *cWdl = Wdl, *cWrh = Wrh, *cWrl = Wrl,
                             *cWsh = Wsh, *cWsl = Wsl;
        void* args[] = {
            (void*)&Xs0h, (void*)&Xs0l, (void*)&Xs1h, (void*)&Xs1l,
            (void*)&cWdh, (void*)&cWdl, (void*)&cWrh, (void*)&cWrl,
            (void*)&cWsh, (void*)&cWsl,
            (void*)&br, (void*)&bs, (void*)&out
        };
        hipError_t lerr = hipLaunchCooperativeKernel(
            reinterpret_cast<const void*>(wn_coop),
            dim3(gridn), dim3(256), args, 0, stream);
        coop_ok = (lerr == hipSuccess);
    }

    if (!coop_ok) {
        int L = TFULL;
        int pp = 0;
        for (int i = 0; i < NB; ++i) {
            const int d = 1 << (i % 10);
            const int Lout = L - d;
            const int col0 = TFULL - Lout;
            const int units = ((Lout + 63) >> 6) * BATCH;
            unsigned short* curh = pp ? Xs1h : Xs0h;
            unsigned short* curl = pp ? Xs1l : Xs0l;
            unsigned short* nxth = pp ? Xs0h : Xs1h;
            unsigned short* nxtl = pp ? Xs0l : Xs1l;
            wn_step<<<dim3(units), dim3(256), 0, stream>>>(
                curh, curl, nxth, nxtl,
                Wdh + (size_t)i * 32768, Wdl + (size_t)i * 32768,
                Wrh + (size_t)i * 16384, Wrl + (size_t)i * 16384,
                Wsh + (size_t)i * 16384, Wsl + (size_t)i * 16384,
                br + (size_t)i * RC, bs + (size_t)i * RC,
                out + (size_t)i * BATCH * RC * SKIP_SZ, d, col0);
            pp ^= 1;
            L = Lout;
        }
    }
}

// Round 6
// 796.610 us; speedup vs baseline: 5.9735x; 5.9735x over previous
//
#include <hip/hip_runtime.h>

typedef __attribute__((ext_vector_type(8))) short bf16x8;
typedef __attribute__((ext_vector_type(4))) short bf16x4;
typedef __attribute__((ext_vector_type(4))) float f32x4;

#define TFULL 8192
#define RC 128
#define NB 40
#define BATCH 4
#define SKIP_SZ 4096

// LDS: 4 planes of [64 col][256 B], XOR-swizzled (byte ^= (col&7)<<4).
//   plane 0/1: staged X hi/lo (current tap; tap1 resident at epilogue)
//   plane 2/3: gated hi/lo
#define XPLANE 16384
#define GBASE  (2 * XPLANE)
#define LDS_BYTES (4 * XPLANE)   // 65536 B -> 2 WG/CU

__device__ __forceinline__ unsigned short f2bf(float f) {
    unsigned u = __builtin_bit_cast(unsigned, f);
    u += 0x7FFFu + ((u >> 16) & 1u);          // round-to-nearest-even
    return (unsigned short)(u >> 16);
}
__device__ __forceinline__ float bf2f(unsigned short h) {
    unsigned u = ((unsigned)h) << 16;
    return __builtin_bit_cast(float, u);
}
// tanh(y)*sigmoid(y) via one fast exp (clamped; saturation exact).
__device__ __forceinline__ float gatef(float y) {
    float yc = fminf(fmaxf(y, -30.f), 30.f);
    float e  = __expf(-yc);
    float e2 = e * e;
    return (1.f - e2) * __builtin_amdgcn_rcpf(1.f + e2)
                      * __builtin_amdgcn_rcpf(1.f + e);
}

// ---------------------------------------------------------------------------
// Pre-pass 1: transpose x [B][128ch][8192col] fp32 -> hi/lo bf16 [B][col][ch]
// ---------------------------------------------------------------------------
__global__ __launch_bounds__(256) void xpose_split(
    const float* __restrict__ x,
    unsigned short* __restrict__ Xh, unsigned short* __restrict__ Xl)
{
    __shared__ float t[32][65];
    const int col0 = blockIdx.x * 64;
    const int ch0  = blockIdx.y * 32;
    const int b    = blockIdx.z;
    const int tid  = threadIdx.x;
    const int tx = tid & 63, ty = tid >> 6;
#pragma unroll
    for (int i = 0; i < 8; ++i) {
        int ch = ty + i * 4;
        t[ch][tx] = x[((size_t)(b * RC + ch0 + ch)) * TFULL + col0 + tx];
    }
    __syncthreads();
    for (int idx = tid; idx < 64 * 32; idx += 256) {
        int col = idx >> 5, ch = idx & 31;
        float v = t[ch][col];
        unsigned short h = f2bf(v);
        unsigned short l = f2bf(v - bf2f(h));
        size_t off = ((size_t)(b * TFULL + col0 + col)) * RC + ch0 + ch;
        Xh[off] = h;
        Xl[off] = l;
    }
}

// ---------------------------------------------------------------------------
// Pre-pass 2: pack weights into per-MFMA-A-fragment layout, hi/lo bf16.
// A[m][k]: lane l holds rows m=16*mf+(l&15), k = 32*ks + (l>>4)*8 + j.
// Dilated k = tap*128 + i. Dst flat: ((blk*KS*8 + ks*8 + mf)*64 + lane)*8 + j.
// ---------------------------------------------------------------------------
__global__ __launch_bounds__(256) void wpack(
    const float* __restrict__ Wd, const float* __restrict__ Wr, const float* __restrict__ Ws,
    unsigned short* __restrict__ Wdh, unsigned short* __restrict__ Wdl,
    unsigned short* __restrict__ Wrh, unsigned short* __restrict__ Wrl,
    unsigned short* __restrict__ Wsh, unsigned short* __restrict__ Wsl)
{
    const int Nd = NB * 4096;
    const int Nr = NB * 2048;
    int id = blockIdx.x * 256 + threadIdx.x;
    const float* src;
    unsigned short *dh, *dl;
    int blk, rloc;
    bool dil = false;
    size_t dbase;
    if (id < Nd)               { dil = true; blk = id >> 12; rloc = id & 4095; dh = Wdh; dl = Wdl; src = Wd; dbase = (size_t)id * 8; }
    else if (id < Nd + Nr)     { int t = id - Nd;      blk = t >> 11; rloc = t & 2047; dh = Wrh; dl = Wrl; src = Wr; dbase = (size_t)t * 8; }
    else if (id < Nd + 2 * Nr) { int t = id - Nd - Nr; blk = t >> 11; rloc = t & 2047; dh = Wsh; dl = Wsl; src = Ws; dbase = (size_t)t * 8; }
    else return;
    const int ks = rloc >> 9, mf = (rloc >> 6) & 7, lane = rloc & 63;
    const int m = mf * 16 + (lane & 15);
    const int kb = ks * 32 + ((lane >> 4) << 3);
    bf16x8 hv, lv;
#pragma unroll
    for (int j = 0; j < 8; ++j) {
        int k = kb + j;
        float w;
        if (dil) {
            int tap = k >> 7, i = k & 127;
            w = src[((((size_t)blk * 128 + m) * 128) + i) * 2 + tap];
        } else {
            w = src[(((size_t)blk * 128 + m) * 128) + k];
        }
        unsigned short h = f2bf(w);
        hv[j] = (short)h;
        lv[j] = (short)f2bf(w - bf2f(h));
    }
    *(bf16x8*)(dh + dbase) = hv;
    *(bf16x8*)(dl + dbase) = lv;
}

// ---------------------------------------------------------------------------
// One WaveNet block step. 512 thr = 8 waves; WG tile = 128 out-ch x 64 cols;
// wave = 16 out-ch (mf slot = wave) x 64 cols (4 nf fragments).
// unit u: b = u&3, tile = u>>2. Taps staged sequentially into X planes.
// 3-product hi/lo bf16 splitting throughout.
// ---------------------------------------------------------------------------
__global__ __launch_bounds__(512, 4) void wn_step(
    const unsigned short* __restrict__ curh, const unsigned short* __restrict__ curl,
    unsigned short* __restrict__ nxth, unsigned short* __restrict__ nxtl,
    const unsigned short* __restrict__ Wdh_i, const unsigned short* __restrict__ Wdl_i,
    const unsigned short* __restrict__ Wrh_i, const unsigned short* __restrict__ Wrl_i,
    const unsigned short* __restrict__ Wsh_i, const unsigned short* __restrict__ Wsl_i,
    const float* __restrict__ br, const float* __restrict__ bs,
    float* __restrict__ skip, int d, int col0)
{
    __shared__ char lds[LDS_BYTES];

    const int tid  = threadIdx.x;
    const int lane = tid & 63;
    const int wave = tid >> 6;            // 0..7 = mf slot
    const int l15  = lane & 15, lq = lane >> 4;
    const int u    = blockIdx.x;
    const int b    = u & 3;
    const int tile0 = col0 + (u >> 2) * 64;
    const size_t xbase = (size_t)b * TFULL * RC;

    f32x4 acc[4];
#pragma unroll
    for (int nf = 0; nf < 4; ++nf) acc[nf] = (f32x4){0.f, 0.f, 0.f, 0.f};

#pragma unroll
    for (int tap = 0; tap < 2; ++tap) {
        __syncthreads();   // WAR: prior reads of X planes complete
        {   // stage this tap hi+lo: 2 planes x 64 col x 256 B = 32 KB, 4 rounds
            const int cshift = tap ? 0 : d;
            float4 v[4];
#pragma unroll
            for (int q = 0; q < 4; ++q) {
                const int cid   = q * 512 + tid;       // 0..2047 chunk id
                const int hl    = cid >> 10;
                const int cw    = cid & 1023;
                const int col   = cw >> 4;
                const int chunk = cw & 15;
                int cg_ = tile0 + col;
                cg_ = cg_ > TFULL - 1 ? TFULL - 1 : cg_;   // tail clamp
                cg_ -= cshift;
                const unsigned short* src = hl ? curl : curh;
                v[q] = *(const float4*)(src + xbase + (size_t)cg_ * RC + chunk * 8);
            }
#pragma unroll
            for (int q = 0; q < 4; ++q) {
                const int cid   = q * 512 + tid;
                const int hl    = cid >> 10;
                const int cw    = cid & 1023;
                const int col   = cw >> 4;
                const int chunk = cw & 15;
                char* p = lds + hl * XPLANE + col * 256
                          + ((chunk * 16) ^ ((col & 7) << 4));
                *(float4*)p = v[q];
            }
        }
        __syncthreads();

#pragma unroll
        for (int kk = 0; kk < 4; ++kk) {
            const int ks = tap * 4 + kk;
            const size_t wi = ((size_t)(ks * 8 + wave) * 64 + lane) * 8;
            bf16x8 ah = *(const bf16x8*)(Wdh_i + wi);
            bf16x8 al = *(const bf16x8*)(Wdl_i + wi);
            bf16x8 bh[4], bl[4];
#pragma unroll
            for (int nf = 0; nf < 4; ++nf) {
                const int col = nf * 16 + l15;
                const int byo = (kk * 64 + lq * 16) ^ ((col & 7) << 4);
                const char* pb = lds + col * 256 + byo;
                bh[nf] = *(const bf16x8*)pb;
                bl[nf] = *(const bf16x8*)(pb + XPLANE);
            }
#pragma unroll
            for (int nf = 0; nf < 4; ++nf) {
                acc[nf] = __builtin_amdgcn_mfma_f32_16x16x32_bf16(ah, bh[nf], acc[nf], 0, 0, 0);
                acc[nf] = __builtin_amdgcn_mfma_f32_16x16x32_bf16(ah, bl[nf], acc[nf], 0, 0, 0);
                acc[nf] = __builtin_amdgcn_mfma_f32_16x16x32_bf16(al, bh[nf], acc[nf], 0, 0, 0);
            }
        }
    }

    // ---- gate + write gated hi/lo to LDS planes 2/3
    const int ch0 = wave * 16 + lq * 4;
#pragma unroll
    for (int nf = 0; nf < 4; ++nf) {
        const int n   = nf * 16 + l15;
        const int byo = (ch0 * 2) ^ ((n & 7) << 4);
        char* pg = lds + GBASE + n * 256 + byo;
        bf16x4 hv, lv;
#pragma unroll
        for (int r = 0; r < 4; ++r) {
            float g = gatef(acc[nf][r]);
            unsigned short h = f2bf(g);
            hv[r] = (short)h;
            lv[r] = (short)f2bf(g - bf2f(h));
        }
        *(bf16x4*)pg = hv;
        *(bf16x4*)(pg + XPLANE) = lv;
    }
    __syncthreads();

    // ---- res & skip 1x1 GEMMs: K = 128 over gated
    f32x4 accr[4], accs[4];
#pragma unroll
    for (int nf = 0; nf < 4; ++nf) {
        accr[nf] = (f32x4){0.f, 0.f, 0.f, 0.f};
        accs[nf] = (f32x4){0.f, 0.f, 0.f, 0.f};
    }
#pragma unroll
    for (int ks = 0; ks < 4; ++ks) {
        const size_t wi = ((size_t)(ks * 8 + wave) * 64 + lane) * 8;
        bf16x8 rh = *(const bf16x8*)(Wrh_i + wi);
        bf16x8 rl = *(const bf16x8*)(Wrl_i + wi);
        bf16x8 sh = *(const bf16x8*)(Wsh_i + wi);
        bf16x8 sl = *(const bf16x8*)(Wsl_i + wi);
        bf16x8 gh[4], gl2[4];
#pragma unroll
        for (int nf = 0; nf < 4; ++nf) {
            const int col = nf * 16 + l15;
            const int byo = (ks * 64 + lq * 16) ^ ((col & 7) << 4);
            const char* pg = lds + GBASE + col * 256 + byo;
            gh[nf]  = *(const bf16x8*)pg;
            gl2[nf] = *(const bf16x8*)(pg + XPLANE);
        }
#pragma unroll
        for (int nf = 0; nf < 4; ++nf) {
            accr[nf] = __builtin_amdgcn_mfma_f32_16x16x32_bf16(rh, gh[nf],  accr[nf], 0, 0, 0);
            accr[nf] = __builtin_amdgcn_mfma_f32_16x16x32_bf16(rh, gl2[nf], accr[nf], 0, 0, 0);
            accr[nf] = __builtin_amdgcn_mfma_f32_16x16x32_bf16(rl, gh[nf],  accr[nf], 0, 0, 0);
            accs[nf] = __builtin_amdgcn_mfma_f32_16x16x32_bf16(sh, gh[nf],  accs[nf], 0, 0, 0);
            accs[nf] = __builtin_amdgcn_mfma_f32_16x16x32_bf16(sh, gl2[nf], accs[nf], 0, 0, 0);
            accs[nf] = __builtin_amdgcn_mfma_f32_16x16x32_bf16(sl, gh[nf],  accs[nf], 0, 0, 0);
        }
    }

    // ---- epilogue: residual add (input = staged tap1 in planes 0/1), store
    const int nt = TFULL - tile0 < 64 ? TFULL - tile0 : 64;
    const float4 brv = *(const float4*)(br + ch0);
    const float4 bsv = *(const float4*)(bs + ch0);
#pragma unroll
    for (int nf = 0; nf < 4; ++nf) {
        const int n = nf * 16 + l15;
        const int c = tile0 + n;
        const int byo = (ch0 * 2) ^ ((n & 7) << 4);
        const char* pr = lds + n * 256 + byo;
        bf16x4 ih = *(const bf16x4*)pr;
        bf16x4 il = *(const bf16x4*)(pr + XPLANE);
        bf16x4 oh, ol;
        float sk[4];
#pragma unroll
        for (int r = 0; r < 4; ++r) {
            float inv = bf2f((unsigned short)ih[r]) + bf2f((unsigned short)il[r]);
            float rv = accr[nf][r] + ((const float*)&brv)[r] + inv;
            unsigned short h = f2bf(rv);
            oh[r] = (short)h;
            ol[r] = (short)f2bf(rv - bf2f(h));
            sk[r] = accs[nf][r] + ((const float*)&bsv)[r];
        }
        if (n < nt) {
            const size_t off = xbase + (size_t)c * RC + ch0;
            *(bf16x4*)(nxth + off) = oh;
            *(bf16x4*)(nxtl + off) = ol;
            if (c >= TFULL - SKIP_SZ) {
                float* sp = skip + ((size_t)b * RC + ch0) * SKIP_SZ + (c - (TFULL - SKIP_SZ));
#pragma unroll
                for (int r = 0; r < 4; ++r) sp[(size_t)r * SKIP_SZ] = sk[r];
            }
        }
    }
}

extern "C" void kernel_launch(void* const* d_in, const int* in_sizes, int n_in,
                              void* d_out, int out_size, void* d_ws, size_t ws_size,
                              hipStream_t stream) {
    const float* x  = (const float*)d_in[0];
    const float* Wd = (const float*)d_in[1];
    const float* Wr = (const float*)d_in[2];
    const float* br = (const float*)d_in[3];
    const float* Ws = (const float*)d_in[4];
    const float* bs = (const float*)d_in[5];
    float* out = (float*)d_out;

    const size_t SLOT = (size_t)BATCH * TFULL * RC;
    unsigned short* Xs0h = (unsigned short*)d_ws;
    unsigned short* Xs0l = Xs0h + SLOT;
    unsigned short* Xs1h = Xs0l + SLOT;
    unsigned short* Xs1l = Xs1h + SLOT;
    unsigned short* Wdh = Xs1l + SLOT;
    unsigned short* Wdl = Wdh + (size_t)NB * 32768;
    unsigned short* Wrh = Wdl + (size_t)NB * 32768;
    unsigned short* Wrl = Wrh + (size_t)NB * 16384;
    unsigned short* Wsh = Wrl + (size_t)NB * 16384;
    unsigned short* Wsl = Wsh + (size_t)NB * 16384;

    xpose_split<<<dim3(TFULL / 64, RC / 32, BATCH), 256, 0, stream>>>(x, Xs0h, Xs0l);
    {
        int total = NB * 4096 + 2 * NB * 2048;
        wpack<<<dim3((total + 255) / 256), 256, 0, stream>>>(Wd, Wr, Ws, Wdh, Wdl, Wrh, Wrl, Wsh, Wsl);
    }

    int L = TFULL;
    int pp = 0;
    for (int i = 0; i < NB; ++i) {
        const int d = 1 << (i % 10);
        const int Lout = L - d;
        const int col0 = TFULL - Lout;
        const int units = ((Lout + 63) >> 6) * BATCH;
        unsigned short* curh = pp ? Xs1h : Xs0h;
        unsigned short* curl = pp ? Xs1l : Xs0l;
        unsigned short* nxth = pp ? Xs0h : Xs1h;
        unsigned short* nxtl = pp ? Xs0l : Xs1l;
        wn_step<<<dim3(units), dim3(512), 0, stream>>>(
            curh, curl, nxth, nxtl,
            Wdh + (size_t)i * 32768, Wdl + (size_t)i * 32768,
            Wrh + (size_t)i * 16384, Wrl + (size_t)i * 16384,
            Wsh + (size_t)i * 16384, Wsl + (size_t)i * 16384,
            br + (size_t)i * RC, bs + (size_t)i * RC,
            out + (size_t)i * BATCH * RC * SKIP_SZ, d, col0);
        pp ^= 1;
        L = Lout;
    }
}